// Round 8
// baseline (79.255 us; speedup 1.0000x reference)
//
#include <hip/hip_runtime.h>
#include <cfloat>

// Persistent waves: 2048 blocks x 4 waves = 8192 waves; each wave processes
// rows row0, row0+8192, ... (8 rows) with a 1-deep register prefetch:
// next row's loads are issued BEFORE the current row's selection, so HBM
// latency hides under ~1500 cyc of selection compute.
//
// Per-row selection (exact): t0 = 1.84 constant; compact candidates
// (x >= t0, E[count] ~ 33 for iid N(0,1)) into a per-wave LDS slot via
// ballot+mbcnt offsets, bitonic-sort 64 across lanes, kth = sorted[48].
// Fallback (rare, wave-uniform): head-sort + exact value-ascent.

typedef float f32x4 __attribute__((ext_vector_type(4)));

static __device__ __forceinline__ float wave_min64(float v) {
#pragma unroll
    for (int d = 1; d < 64; d <<= 1) v = fminf(v, __shfl_xor(v, d));
    return v;
}
static __device__ __forceinline__ float wave_sum64(float v) {
#pragma unroll
    for (int d = 1; d < 64; d <<= 1) v += __shfl_xor(v, d);
    return v;
}
static __device__ __forceinline__ int wave_sum64_i(int v) {
#pragma unroll
    for (int d = 1; d < 64; d <<= 1) v += __shfl_xor(v, d);
    return v;
}
static __device__ __forceinline__ unsigned lanes_below(unsigned long long m) {
    return __builtin_amdgcn_mbcnt_hi((unsigned)(m >> 32),
           __builtin_amdgcn_mbcnt_lo((unsigned)m, 0u));
}

struct R16 { float4 a, b, c, d; };

static __device__ __forceinline__ R16 load_row(const float4* __restrict__ rp, int lane) {
    R16 r;
    r.a = rp[lane];
    r.b = rp[64 + lane];
    r.c = rp[128 + lane];
    r.d = rp[192 + lane];
    return r;
}

#define APPLY16(OP) \
    OP(r.a.x) OP(r.a.y) OP(r.a.z) OP(r.a.w) \
    OP(r.b.x) OP(r.b.y) OP(r.b.z) OP(r.b.w) \
    OP(r.c.x) OP(r.c.y) OP(r.c.z) OP(r.c.w) \
    OP(r.d.x) OP(r.d.y) OP(r.d.z) OP(r.d.w)

static __device__ __forceinline__ float kth_of_row(const R16& r, int lane, float* sm) {
    const float t0 = 1.84f;   // E[count >= t0] ~= 33 per row

    // ---- ballot+mbcnt compaction into LDS (no serial scan) ----
    unsigned base = 0;
#define SLOT(X) { \
        const bool p = (X) >= t0; \
        const unsigned long long m = __ballot(p); \
        if (p) sm[base + lanes_below(m)] = (X); \
        base += (unsigned)__popcll(m); }
    APPLY16(SLOT)
#undef SLOT
    const unsigned C = base;   // wave-uniform

    if (C >= 16 && C <= 64) {
        float y = (lane < (int)C) ? sm[lane] : -FLT_MAX;
        // bitonic sort ascending across lanes (lane 63 = max)
#pragma unroll
        for (int k = 2; k <= 64; k <<= 1) {
#pragma unroll
            for (int j = k >> 1; j > 0; j >>= 1) {
                const float p = __shfl_xor(y, j);
                const bool keep_min = (((lane & k) == 0) == ((lane & j) == 0));
                y = keep_min ? fminf(y, p) : fmaxf(y, p);
            }
        }
        return __shfl(y, 48);   // 16th largest
    }

    // ---- fallback (rare, wave-uniform): head-sort + exact value ascent ----
    float h = -FLT_MAX;
#define HMAX(X) h = fmaxf(h, (X));
    APPLY16(HMAX)
#undef HMAX
#pragma unroll
    for (int k = 2; k <= 64; k <<= 1) {
#pragma unroll
        for (int j = k >> 1; j > 0; j >>= 1) {
            const float p = __shfl_xor(h, j);
            const bool keep_min = (((lane & k) == 0) == ((lane & j) == 0));
            h = keep_min ? fminf(h, p) : fmaxf(h, p);
        }
    }
    const float tl = __shfl(h, 48);

    float m = FLT_MAX;
#define CANDMIN(X) m = fminf(m, ((X) >= tl) ? (X) : FLT_MAX);
    APPLY16(CANDMIN)
#undef CANDMIN
    float g = wave_min64(m);
    for (;;) {
        int cnt = 0;
        float nm = FLT_MAX;
#define STEP(X) { const bool gt = (X) > g; cnt += gt ? 1 : 0; nm = fminf(nm, gt ? (X) : FLT_MAX); }
        APPLY16(STEP)
#undef STEP
        if (wave_sum64_i(cnt) <= 15) break;
        g = wave_min64(nm);
    }
    return g;
}

static __device__ __forceinline__ void epilogue(const R16& r, float kth,
                                                f32x4* __restrict__ op, int lane) {
    const float z0  = (r.a.x >= kth) ? r.a.x : 0.0f;  const float z1  = (r.a.y >= kth) ? r.a.y : 0.0f;
    const float z2  = (r.a.z >= kth) ? r.a.z : 0.0f;  const float z3  = (r.a.w >= kth) ? r.a.w : 0.0f;
    const float z4  = (r.b.x >= kth) ? r.b.x : 0.0f;  const float z5  = (r.b.y >= kth) ? r.b.y : 0.0f;
    const float z6  = (r.b.z >= kth) ? r.b.z : 0.0f;  const float z7  = (r.b.w >= kth) ? r.b.w : 0.0f;
    const float z8  = (r.c.x >= kth) ? r.c.x : 0.0f;  const float z9  = (r.c.y >= kth) ? r.c.y : 0.0f;
    const float z10 = (r.c.z >= kth) ? r.c.z : 0.0f;  const float z11 = (r.c.w >= kth) ? r.c.w : 0.0f;
    const float z12 = (r.d.x >= kth) ? r.d.x : 0.0f;  const float z13 = (r.d.y >= kth) ? r.d.y : 0.0f;
    const float z14 = (r.d.z >= kth) ? r.d.z : 0.0f;  const float z15 = (r.d.w >= kth) ? r.d.w : 0.0f;

    float s = (((z0 + z1) + (z2 + z3)) + ((z4 + z5) + (z6 + z7)))
            + (((z8 + z9) + (z10 + z11)) + ((z12 + z13) + (z14 + z15)));
    s = wave_sum64(s);
    const float inv = 1.0f / s;

    f32x4 o;
    o.x = z0 * inv;  o.y = z1 * inv;  o.z = z2 * inv;  o.w = z3 * inv;
    __builtin_nontemporal_store(o, &op[lane]);
    o.x = z4 * inv;  o.y = z5 * inv;  o.z = z6 * inv;  o.w = z7 * inv;
    __builtin_nontemporal_store(o, &op[64 + lane]);
    o.x = z8 * inv;  o.y = z9 * inv;  o.z = z10 * inv; o.w = z11 * inv;
    __builtin_nontemporal_store(o, &op[128 + lane]);
    o.x = z12 * inv; o.y = z13 * inv; o.z = z14 * inv; o.w = z15 * inv;
    __builtin_nontemporal_store(o, &op[192 + lane]);
}

__global__ __launch_bounds__(256) void kmax_norm_kernel(const float* __restrict__ in,
                                                        float* __restrict__ out,
                                                        int nrows, int nwaves) {
    __shared__ float smbuf[4][64];

    const int lane = threadIdx.x & 63;
    const int wid  = threadIdx.x >> 6;
    float* const sm = smbuf[wid];

    int row = blockIdx.x * 4 + wid;     // global wave id
    if (row >= nrows) return;

    const float4* __restrict__ ip = reinterpret_cast<const float4*>(in);
    f32x4* __restrict__ opb       = reinterpret_cast<f32x4*>(out);

    R16 cur = load_row(ip + (size_t)row * 256, lane);
    for (;;) {
        const int nrow = row + nwaves;
        const bool has = (nrow < nrows);
        R16 nxt;
        if (has) nxt = load_row(ip + (size_t)nrow * 256, lane);  // prefetch next row

        const float kth = kth_of_row(cur, lane, sm);
        epilogue(cur, kth, opb + (size_t)row * 256, lane);

        if (!has) break;
        cur = nxt;            // vmcnt wait lands here, after selection+store
        row = nrow;
    }
}

extern "C" void kernel_launch(void* const* d_in, const int* in_sizes, int n_in,
                              void* d_out, int out_size, void* d_ws, size_t ws_size,
                              hipStream_t stream) {
    (void)n_in; (void)d_ws; (void)ws_size; (void)out_size;
    const float* in = (const float*)d_in[0];
    float* out = (float*)d_out;
    const int nrows = in_sizes[0] / 1024;            // 16*4096 = 65536
    int blocks = (nrows + 3) / 4;
    if (blocks > 2048) blocks = 2048;                // persistent: 8192 waves, 8 rows/wave
    const int nwaves = blocks * 4;
    kmax_norm_kernel<<<blocks, 256, 0, stream>>>(in, out, nrows, nwaves);
}

// Round 9
// 73.732 us; speedup vs baseline: 1.0749x; 1.0749x over previous
//
#include <hip/hip_runtime.h>
#include <cfloat>

// One 64-lane wave per row of 1024 floats; lane i owns j*256 + i*4 + {0..3}.
//
// kth selection, fast path (exact):
//   t0 = 1.84 (constant). C = count(x >= t0) over the row.
//   If 16 <= C <= 64: compact the C candidates into LDS (prefix-sum scatter),
//   one lane-wide bitonic sort of 64 (pad -inf), kth = sorted[48]
//   (rank-16-from-top; valid because C >= 16 and every top-16 value >= t0).
//   Else: fallback = per-lane-max head-sort for a row-derived t0', then
//   exact value-ascent (R3 algorithm).
//
// Memory-system-bound: per replay ~131 MB HBM read (rest of the 268 MB input
// L3-hits) + 262 MB NT write; 5.3 TB/s HBM-sum = 85% of float4-copy ceiling,
// 7.1 TB/s counting L3-served reads. Compute (VALUBusy ~35%) off critical path.

typedef float f32x4 __attribute__((ext_vector_type(4)));

static __device__ __forceinline__ float wave_min64(float v) {
#pragma unroll
    for (int d = 1; d < 64; d <<= 1) v = fminf(v, __shfl_xor(v, d));
    return v;
}
static __device__ __forceinline__ float wave_sum64(float v) {
#pragma unroll
    for (int d = 1; d < 64; d <<= 1) v += __shfl_xor(v, d);
    return v;
}
static __device__ __forceinline__ int wave_sum64_i(int v) {
#pragma unroll
    for (int d = 1; d < 64; d <<= 1) v += __shfl_xor(v, d);
    return v;
}

__global__ __launch_bounds__(256) void kmax_norm_kernel(const float* __restrict__ in,
                                                        float* __restrict__ out,
                                                        int nrows) {
    __shared__ float sm[4][64];

    const int lane = threadIdx.x & 63;
    const int wid  = threadIdx.x >> 6;
    const int row  = blockIdx.x * 4 + wid;
    if (row >= nrows) return;

    const float4* __restrict__ rp = reinterpret_cast<const float4*>(in) + (size_t)row * 256;
    f32x4* __restrict__ op        = reinterpret_cast<f32x4*>(out) + (size_t)row * 256;

    const float4 v0 = rp[lane];
    const float4 v1 = rp[64 + lane];
    const float4 v2 = rp[128 + lane];
    const float4 v3 = rp[192 + lane];

    const float x0  = v0.x, x1  = v0.y, x2  = v0.z, x3  = v0.w;
    const float x4  = v1.x, x5  = v1.y, x6  = v1.z, x7  = v1.w;
    const float x8  = v2.x, x9  = v2.y, x10 = v2.z, x11 = v2.w;
    const float x12 = v3.x, x13 = v3.y, x14 = v3.z, x15 = v3.w;

    const float t0 = 1.84f;   // E[count >= t0] ~= 33 per row for N(0,1)

    // per-lane candidate count
    int c = 0;
#define CNT(X) c += ((X) >= t0) ? 1 : 0;
    CNT(x0)  CNT(x1)  CNT(x2)  CNT(x3)  CNT(x4)  CNT(x5)  CNT(x6)  CNT(x7)
    CNT(x8)  CNT(x9)  CNT(x10) CNT(x11) CNT(x12) CNT(x13) CNT(x14) CNT(x15)
#undef CNT

    // inclusive scan across lanes
    int pinc = c;
#pragma unroll
    for (int d = 1; d < 64; d <<= 1) {
        const int t = __shfl_up(pinc, d);
        if (lane >= d) pinc += t;
    }
    const int C = __shfl(pinc, 63);

    float kth;
    if (C >= 16 && C <= 64) {
        // ---- fast path: compact candidates to LDS, bitonic-sort 64 ----
        int idx = pinc - c;   // exclusive offset
#define SCAT(X) if ((X) >= t0) { sm[wid][idx] = (X); ++idx; }
        SCAT(x0)  SCAT(x1)  SCAT(x2)  SCAT(x3)  SCAT(x4)  SCAT(x5)  SCAT(x6)  SCAT(x7)
        SCAT(x8)  SCAT(x9)  SCAT(x10) SCAT(x11) SCAT(x12) SCAT(x13) SCAT(x14) SCAT(x15)
#undef SCAT
        float y = (lane < C) ? sm[wid][lane] : -FLT_MAX;
        // bitonic sort ascending across lanes (lane 63 = max)
#pragma unroll
        for (int k = 2; k <= 64; k <<= 1) {
#pragma unroll
            for (int j = k >> 1; j > 0; j >>= 1) {
                const float p = __shfl_xor(y, j);
                const bool keep_min = (((lane & k) == 0) == ((lane & j) == 0));
                y = keep_min ? fminf(y, p) : fmaxf(y, p);
            }
        }
        kth = __shfl(y, 48);   // 16th largest
    } else {
        // ---- fallback (rare, wave-uniform): head-sort + exact value ascent ----
        float h = fmaxf(fmaxf(fmaxf(fmaxf(x0, x1), fmaxf(x2, x3)),
                              fmaxf(fmaxf(x4, x5), fmaxf(x6, x7))),
                        fmaxf(fmaxf(fmaxf(x8, x9), fmaxf(x10, x11)),
                              fmaxf(fmaxf(x12, x13), fmaxf(x14, x15))));
#pragma unroll
        for (int k = 2; k <= 64; k <<= 1) {
#pragma unroll
            for (int j = k >> 1; j > 0; j >>= 1) {
                const float p = __shfl_xor(h, j);
                const bool keep_min = (((lane & k) == 0) == ((lane & j) == 0));
                h = keep_min ? fminf(h, p) : fmaxf(h, p);
            }
        }
        const float tl = __shfl(h, 48);   // 16th-largest head: lower bound on kth

        float m = FLT_MAX;
#define CANDMIN(X) m = fminf(m, ((X) >= tl) ? (X) : FLT_MAX);
        CANDMIN(x0)  CANDMIN(x1)  CANDMIN(x2)  CANDMIN(x3)
        CANDMIN(x4)  CANDMIN(x5)  CANDMIN(x6)  CANDMIN(x7)
        CANDMIN(x8)  CANDMIN(x9)  CANDMIN(x10) CANDMIN(x11)
        CANDMIN(x12) CANDMIN(x13) CANDMIN(x14) CANDMIN(x15)
#undef CANDMIN
        float g = wave_min64(m);
        for (;;) {
            int cnt = 0;
            float nm = FLT_MAX;
#define STEP(X) { const bool gt = (X) > g; cnt += gt ? 1 : 0; nm = fminf(nm, gt ? (X) : FLT_MAX); }
            STEP(x0)  STEP(x1)  STEP(x2)  STEP(x3)
            STEP(x4)  STEP(x5)  STEP(x6)  STEP(x7)
            STEP(x8)  STEP(x9)  STEP(x10) STEP(x11)
            STEP(x12) STEP(x13) STEP(x14) STEP(x15)
#undef STEP
            if (wave_sum64_i(cnt) <= 15) break;
            g = wave_min64(nm);
        }
        kth = g;
    }

    // ---- fused mask + sum + normalize + store ----
    const float z0  = (x0  >= kth) ? x0  : 0.0f;  const float z1  = (x1  >= kth) ? x1  : 0.0f;
    const float z2  = (x2  >= kth) ? x2  : 0.0f;  const float z3  = (x3  >= kth) ? x3  : 0.0f;
    const float z4  = (x4  >= kth) ? x4  : 0.0f;  const float z5  = (x5  >= kth) ? x5  : 0.0f;
    const float z6  = (x6  >= kth) ? x6  : 0.0f;  const float z7  = (x7  >= kth) ? x7  : 0.0f;
    const float z8  = (x8  >= kth) ? x8  : 0.0f;  const float z9  = (x9  >= kth) ? x9  : 0.0f;
    const float z10 = (x10 >= kth) ? x10 : 0.0f;  const float z11 = (x11 >= kth) ? x11 : 0.0f;
    const float z12 = (x12 >= kth) ? x12 : 0.0f;  const float z13 = (x13 >= kth) ? x13 : 0.0f;
    const float z14 = (x14 >= kth) ? x14 : 0.0f;  const float z15 = (x15 >= kth) ? x15 : 0.0f;

    float s = (((z0 + z1) + (z2 + z3)) + ((z4 + z5) + (z6 + z7)))
            + (((z8 + z9) + (z10 + z11)) + ((z12 + z13) + (z14 + z15)));
    s = wave_sum64(s);
    const float inv = 1.0f / s;

    f32x4 o;
    o.x = z0 * inv;  o.y = z1 * inv;  o.z = z2 * inv;  o.w = z3 * inv;
    __builtin_nontemporal_store(o, &op[lane]);
    o.x = z4 * inv;  o.y = z5 * inv;  o.z = z6 * inv;  o.w = z7 * inv;
    __builtin_nontemporal_store(o, &op[64 + lane]);
    o.x = z8 * inv;  o.y = z9 * inv;  o.z = z10 * inv; o.w = z11 * inv;
    __builtin_nontemporal_store(o, &op[128 + lane]);
    o.x = z12 * inv; o.y = z13 * inv; o.z = z14 * inv; o.w = z15 * inv;
    __builtin_nontemporal_store(o, &op[192 + lane]);
}

extern "C" void kernel_launch(void* const* d_in, const int* in_sizes, int n_in,
                              void* d_out, int out_size, void* d_ws, size_t ws_size,
                              hipStream_t stream) {
    (void)n_in; (void)d_ws; (void)ws_size; (void)out_size;
    const float* in = (const float*)d_in[0];
    float* out = (float*)d_out;
    const int nrows = in_sizes[0] / 1024;           // 16*4096 = 65536
    const int blocks = (nrows + 3) / 4;             // 4 waves (rows) per 256-thread block
    kmax_norm_kernel<<<blocks, 256, 0, stream>>>(in, out, nrows);
}